// Round 2
// baseline (66.586 us; speedup 1.0000x reference)
//
#include <hip/hip_runtime.h>

// loss = || F^T F - S^T S ||_F^2 / 2^38
// F = input.reshape(64, 8192).T, S = target.reshape(64, 8192).T
// Exact rewrite of sum((FF^T+c)^d + (SS^T+c)^d - 2(FS^T+c)^d) for c=0, d=2:
//   sum_ij (f_i.f_j)^2 = ||F^T F||_F^2  etc., cross term = <F^T F, S^T S>.
//
// Structure notes (measured):
// - 2 dispatches is optimal. Fused single-dispatch with in-ws grid barrier
//   cost +27 us (R6) vs ~3.7 us per dispatch boundary (R2->R3).
// - R7: the ~40.4 us / 256 MiB fillBufferAligned per iteration is
//   UNCONDITIONAL harness poisoning of d_ws — it persists even when we never
//   touch d_ws. It is a structural floor (same-stream, pre-launch, no overlap
//   possible under graph capture). Controllable budget = dur_us - ~40.4 us.
// - Partials live in module-owned g_ws (4 MiB), fully overwritten each iter.
//
// R8 (this round): reduce_square 64 -> 256 blocks (16 entries/block).
// Theory: 64 blocks used only 64/256 CUs; 4 MiB partial read was
// latency/parallelism-bound (~2.5-3 us). 4x CUs, 4x fewer loads/thread.
// Deterministic final sum order preserved (16 slices x 16-seq, fixed-order
// slice combine). gram_partial untouched for attribution.

#define CH    64
#define KTOT  8192
#define G1    256            // gram blocks
#define KPB   (KTOT / G1)    // 32 k per block
#define KPG   (KPB / 2)      // 16 k per 256-thread group

// 1 / (8192 * 8192 * 64 * 64) = 2^-38
#define NORMF 3.637978807091713e-12f

// Module-owned partial buffer (4 MiB). Zero-init at load; fully overwritten
// by gram_partial before reduce_square reads it, every iteration.
__device__ __attribute__((aligned(16))) float g_ws[G1 * 4096];

__global__ __launch_bounds__(512, 4) void gram_partial(
    const float* __restrict__ in, const float* __restrict__ tg,
    float* __restrict__ out)
{
    // Transposed tiles [k][ch]: fragment reads contiguous in ch.
    __shared__ __attribute__((aligned(16))) float ts_in[KPB][CH];   // 8 KiB
    __shared__ __attribute__((aligned(16))) float ts_tg[KPB][CH];   // 8 KiB
    __shared__ __attribute__((aligned(16))) float red[4096];        // 16 KiB

    const int t  = threadIdx.x;            // 0..511
    const int k0 = blockIdx.x * KPB;

    // zero the output accumulator (ordered before reduce_square's atomics
    // by the kernel boundary)
    if (blockIdx.x == 0 && t == 0) out[0] = 0.f;

    // --- stage: thread t loads one float4 per matrix ---
    {
        const int lch = t >> 3;            // 0..63
        const int lko = (t & 7) << 2;      // 0,4,..,28
        const float4 vi = *(const float4*)(in + lch * KTOT + k0 + lko);
        const float4 vt = *(const float4*)(tg + lch * KTOT + k0 + lko);
        ts_in[lko + 0][lch] = vi.x; ts_in[lko + 1][lch] = vi.y;
        ts_in[lko + 2][lch] = vi.z; ts_in[lko + 3][lch] = vi.w;
        ts_tg[lko + 0][lch] = vt.x; ts_tg[lko + 1][lch] = vt.y;
        ts_tg[lko + 2][lch] = vt.z; ts_tg[lko + 3][lch] = vt.w;
    }
    __syncthreads();

    // --- compute: group g handles kk in [g*KPG, (g+1)*KPG) ---
    const int g   = t >> 8;                // 0..1
    const int tid = t & 255;               // 0..255
    const int ty  = tid >> 4;              // 0..15
    const int tx  = tid & 15;              // 0..15
    const int a0  = ty << 2;
    const int b0  = tx << 2;

    float acc[4][4];
#pragma unroll
    for (int i = 0; i < 4; ++i)
#pragma unroll
        for (int j = 0; j < 4; ++j) acc[i][j] = 0.f;

#pragma unroll
    for (int kk = g * KPG; kk < g * KPG + KPG; ++kk) {
        const float4 av = *(const float4*)&ts_in[kk][a0];
        const float4 bv = *(const float4*)&ts_in[kk][b0];
        const float4 cv = *(const float4*)&ts_tg[kk][a0];
        const float4 dv = *(const float4*)&ts_tg[kk][b0];
        const float aa[4] = {av.x, av.y, av.z, av.w};
        const float bb[4] = {bv.x, bv.y, bv.z, bv.w};
        const float cc[4] = {cv.x, cv.y, cv.z, cv.w};
        const float dd[4] = {dv.x, dv.y, dv.z, dv.w};
#pragma unroll
        for (int i = 0; i < 4; ++i)
#pragma unroll
            for (int j = 0; j < 4; ++j) {
                acc[i][j] = fmaf(aa[i], bb[j], acc[i][j]);
                acc[i][j] = fmaf(-cc[i], dd[j], acc[i][j]);
            }
    }

    // --- block reduce (group 1 -> LDS, group 0 adds) and store ---
    if (g == 1) {
#pragma unroll
        for (int i = 0; i < 4; ++i) {
            float4 v;
            v.x = acc[i][0]; v.y = acc[i][1]; v.z = acc[i][2]; v.w = acc[i][3];
            *(float4*)&red[tid * 16 + i * 4] = v;
        }
    }
    __syncthreads();
    if (g == 0) {
        float* p = g_ws + blockIdx.x * 4096;
#pragma unroll
        for (int i = 0; i < 4; ++i) {
            const float4 r = *(const float4*)&red[tid * 16 + i * 4];
            float4 v;
            v.x = acc[i][0] + r.x; v.y = acc[i][1] + r.y;
            v.z = acc[i][2] + r.z; v.w = acc[i][3] + r.w;
            *(float4*)(p + (a0 + i) * 64 + b0) = v;
        }
    }
}

// R8: 256 blocks x 256 threads. Block b owns 16 gram entries
// [b*16, b*16+16). Thread (sl, el) = (t>>4, t&15) sums 16 partials of
// entry el; 16 slices combined in fixed order -> deterministic.
__global__ __launch_bounds__(256) void reduce_square(float* __restrict__ out)
{
    __shared__ float red2[16][16];             // [slice][entry]
    const int t  = threadIdx.x;
    const int el = t & 15;                     // entry within block
    const int sl = t >> 4;                     // partial slice 0..15
    const int e  = (blockIdx.x << 4) + el;     // gram entry 0..4095

    float s = 0.f;
    const int p0 = sl << 4;
#pragma unroll
    for (int p = p0; p < p0 + 16; ++p)
        s += g_ws[p * 4096 + e];
    red2[sl][el] = s;
    __syncthreads();

    if (t < 64) {                              // wave 0 only
        float sq = 0.f;
        if (t < 16) {
            float tot = 0.f;
#pragma unroll
            for (int s2 = 0; s2 < 16; ++s2)    // fixed order: deterministic
                tot += red2[s2][t];
            sq = tot * tot;
        }
        // lanes 16..63 hold 0; shfl sources for lanes <16 are thus defined
#pragma unroll
        for (int off = 8; off > 0; off >>= 1)
            sq += __shfl_down(sq, off);
        if (t == 0) atomicAdd(out, sq * NORMF);
    }
}

extern "C" void kernel_launch(void* const* d_in, const int* in_sizes, int n_in,
                              void* d_out, int out_size, void* d_ws, size_t ws_size,
                              hipStream_t stream)
{
    const float* in = (const float*)d_in[0];
    const float* tg = (const float*)d_in[1];
    float* out = (float*)d_out;
    (void)d_ws; (void)ws_size;   // workspace untouched (fill is unconditional anyway)

    gram_partial<<<G1, 512, 0, stream>>>(in, tg, out);
    reduce_square<<<256, 256, 0, stream>>>(out);
}

// Round 3
// 63.379 us; speedup vs baseline: 1.0506x; 1.0506x over previous
//
#include <hip/hip_runtime.h>

// loss = || F^T F - S^T S ||_F^2 / 2^38
// F = input.reshape(64, 8192).T, S = target.reshape(64, 8192).T
// Exact rewrite of sum((FF^T+c)^d + (SS^T+c)^d - 2(FS^T+c)^d) for c=0, d=2:
//   sum_ij (f_i.f_j)^2 = ||F^T F||_F^2  etc., cross term = <F^T F, S^T S>.
//
// Structure notes (measured):
// - 2 dispatches is optimal. Fused single-dispatch with in-ws grid barrier
//   cost +27 us (R6) vs ~3.7 us per dispatch boundary (R2->R3).
// - R7: the ~40 us / 256 MiB fillBufferAligned per iteration is UNCONDITIONAL
//   harness poisoning of d_ws — persists even when d_ws is never touched.
//   Structural floor; controllable budget = dur_us - ~40 us.
// - R8: reduce_square at 256 blocks x 16 entries REGRESSED +2.7 us.
//   Cause: wave reads went from one 256B contiguous segment per instruction
//   (64 contiguous entries) to 4 scattered 64B segments (4 slices x 16
//   entries), plus launch ramp on 256 tiny blocks. 64 blocks x 64
//   contiguous entries per wave is the measured optimum. Do not re-raise.
// - Partials live in module-owned g_ws (4 MiB), fully overwritten each iter.
//
// R9 (this round): pure revert of reduce_square to the R7/R0 64-block form.

#define CH    64
#define KTOT  8192
#define G1    256            // gram blocks
#define KPB   (KTOT / G1)    // 32 k per block
#define KPG   (KPB / 2)      // 16 k per 256-thread group

// 1 / (8192 * 8192 * 64 * 64) = 2^-38
#define NORMF 3.637978807091713e-12f

// Module-owned partial buffer (4 MiB). Fully overwritten by gram_partial
// before reduce_square reads it, every iteration.
__device__ __attribute__((aligned(16))) float g_ws[G1 * 4096];

__global__ __launch_bounds__(512, 4) void gram_partial(
    const float* __restrict__ in, const float* __restrict__ tg,
    float* __restrict__ out)
{
    // Transposed tiles [k][ch]: fragment reads contiguous in ch.
    __shared__ __attribute__((aligned(16))) float ts_in[KPB][CH];   // 8 KiB
    __shared__ __attribute__((aligned(16))) float ts_tg[KPB][CH];   // 8 KiB
    __shared__ __attribute__((aligned(16))) float red[4096];        // 16 KiB

    const int t  = threadIdx.x;            // 0..511
    const int k0 = blockIdx.x * KPB;

    // zero the output accumulator (ordered before reduce_square's atomics
    // by the kernel boundary)
    if (blockIdx.x == 0 && t == 0) out[0] = 0.f;

    // --- stage: thread t loads one float4 per matrix ---
    {
        const int lch = t >> 3;            // 0..63
        const int lko = (t & 7) << 2;      // 0,4,..,28
        const float4 vi = *(const float4*)(in + lch * KTOT + k0 + lko);
        const float4 vt = *(const float4*)(tg + lch * KTOT + k0 + lko);
        ts_in[lko + 0][lch] = vi.x; ts_in[lko + 1][lch] = vi.y;
        ts_in[lko + 2][lch] = vi.z; ts_in[lko + 3][lch] = vi.w;
        ts_tg[lko + 0][lch] = vt.x; ts_tg[lko + 1][lch] = vt.y;
        ts_tg[lko + 2][lch] = vt.z; ts_tg[lko + 3][lch] = vt.w;
    }
    __syncthreads();

    // --- compute: group g handles kk in [g*KPG, (g+1)*KPG) ---
    const int g   = t >> 8;                // 0..1
    const int tid = t & 255;               // 0..255
    const int ty  = tid >> 4;              // 0..15
    const int tx  = tid & 15;              // 0..15
    const int a0  = ty << 2;
    const int b0  = tx << 2;

    float acc[4][4];
#pragma unroll
    for (int i = 0; i < 4; ++i)
#pragma unroll
        for (int j = 0; j < 4; ++j) acc[i][j] = 0.f;

#pragma unroll
    for (int kk = g * KPG; kk < g * KPG + KPG; ++kk) {
        const float4 av = *(const float4*)&ts_in[kk][a0];
        const float4 bv = *(const float4*)&ts_in[kk][b0];
        const float4 cv = *(const float4*)&ts_tg[kk][a0];
        const float4 dv = *(const float4*)&ts_tg[kk][b0];
        const float aa[4] = {av.x, av.y, av.z, av.w};
        const float bb[4] = {bv.x, bv.y, bv.z, bv.w};
        const float cc[4] = {cv.x, cv.y, cv.z, cv.w};
        const float dd[4] = {dv.x, dv.y, dv.z, dv.w};
#pragma unroll
        for (int i = 0; i < 4; ++i)
#pragma unroll
            for (int j = 0; j < 4; ++j) {
                acc[i][j] = fmaf(aa[i], bb[j], acc[i][j]);
                acc[i][j] = fmaf(-cc[i], dd[j], acc[i][j]);
            }
    }

    // --- block reduce (group 1 -> LDS, group 0 adds) and store ---
    if (g == 1) {
#pragma unroll
        for (int i = 0; i < 4; ++i) {
            float4 v;
            v.x = acc[i][0]; v.y = acc[i][1]; v.z = acc[i][2]; v.w = acc[i][3];
            *(float4*)&red[tid * 16 + i * 4] = v;
        }
    }
    __syncthreads();
    if (g == 0) {
        float* p = g_ws + blockIdx.x * 4096;
#pragma unroll
        for (int i = 0; i < 4; ++i) {
            const float4 r = *(const float4*)&red[tid * 16 + i * 4];
            float4 v;
            v.x = acc[i][0] + r.x; v.y = acc[i][1] + r.y;
            v.z = acc[i][2] + r.z; v.w = acc[i][3] + r.w;
            *(float4*)(p + (a0 + i) * 64 + b0) = v;
        }
    }
}

// 64 blocks x 256 threads; block b owns 64 gram entries. Wave reads 64
// CONTIGUOUS entries per load instruction (256B/segment) — measured optimum.
__global__ __launch_bounds__(256) void reduce_square(float* __restrict__ out)
{
    // 64 blocks x 64 entries; 4 slices of 64 partials per entry
    __shared__ float red2[4][64];
    const int t  = threadIdx.x;
    const int el = t & 63;                     // entry within block
    const int sl = t >> 6;                     // 0..3
    const int e  = (blockIdx.x << 6) + el;     // gram entry 0..4095

    float s = 0.f;
    const int p0 = sl * (G1 / 4);
#pragma unroll 16
    for (int p = p0; p < p0 + (G1 / 4); ++p)
        s += g_ws[p * 4096 + e];
    red2[sl][el] = s;
    __syncthreads();

    if (t < 64) {                              // wave 0
        float tot = red2[0][t] + red2[1][t] + red2[2][t] + red2[3][t];
        float sq  = tot * tot;
#pragma unroll
        for (int off = 32; off > 0; off >>= 1)
            sq += __shfl_down(sq, off);
        if (t == 0) atomicAdd(out, sq * NORMF);
    }
}

extern "C" void kernel_launch(void* const* d_in, const int* in_sizes, int n_in,
                              void* d_out, int out_size, void* d_ws, size_t ws_size,
                              hipStream_t stream)
{
    const float* in = (const float*)d_in[0];
    const float* tg = (const float*)d_in[1];
    float* out = (float*)d_out;
    (void)d_ws; (void)ws_size;   // workspace untouched (fill is unconditional anyway)

    gram_partial<<<G1, 512, 0, stream>>>(in, tg, out);
    reduce_square<<<64, 256, 0, stream>>>(out);
}